// Round 14
// baseline (1519.019 us; speedup 1.0000x reference)
//
#include <hip/hip_runtime.h>
#include <hip/hip_bf16.h>

#define B_ 2
#define T_ 128
#define U_ 64
#define H_ 1024
#define NO_ 5001

typedef __attribute__((ext_vector_type(8))) short bf16x8;
typedef __attribute__((ext_vector_type(4))) float f32x4;

__device__ __forceinline__ float bf2f(unsigned short s) {
  unsigned int u = ((unsigned int)s) << 16;
  float f; __builtin_memcpy(&f, &u, 4); return f;
}
__device__ __forceinline__ unsigned short f2bf(float f) {
  unsigned int u; __builtin_memcpy(&u, &f, 4);
  u = u + 0x7FFFu + ((u >> 16) & 1u);   // round-to-nearest-even
  return (unsigned short)(u >> 16);
}
__device__ __forceinline__ float fsig(float x) {
  x = fminf(fmaxf(x, -30.f), 30.f);
  float e = __expf(-x);
  return __builtin_amdgcn_rcpf(1.f + e);
}
__device__ __forceinline__ float ftanh(float x) {
  x = fminf(fmaxf(x, -15.f), 15.f);
  float e = __expf(2.f * x);
  return (e - 1.f) * __builtin_amdgcn_rcpf(e + 1.f);
}

__device__ __forceinline__ void gload_lds16(const unsigned short* g, unsigned short* l) {
  __builtin_amdgcn_global_load_lds(
      (const __attribute__((address_space(1))) unsigned int*)g,
      (__attribute__((address_space(3))) unsigned int*)l,
      16, 0, 0);
}

// ---------------- merged f32->bf16 conversions + bias pad (one dispatch) ----------------
#define R_OUTW 1280256
#define R_WIH  (R_OUTW + 2097152)
#define R_WHH  (R_WIH + 2097152)
#define R_ENCW (R_WHH + 262144)
#define R_PRDW (R_ENCW + 262144)
#define R_ENC  (R_PRDW + 65536)
#define R_BIAS (R_ENC + 1280)

__global__ void k_cvt_all(
    const float* __restrict__ outW, const float* __restrict__ Wih,
    const float* __restrict__ Whh,  const float* __restrict__ encW,
    const float* __restrict__ prdW, const float* __restrict__ enc,
    const float* __restrict__ outB,
    unsigned short* __restrict__ outW_bf, unsigned short* __restrict__ Wih_bf,
    unsigned short* __restrict__ Whh_bf,  unsigned short* __restrict__ encW_bf,
    unsigned short* __restrict__ prdW_bf, unsigned short* __restrict__ enc_bf,
    float* __restrict__ biasPad)
{
  int i = blockIdx.x * 256 + threadIdx.x;
  const float* src; unsigned short* dst; int off;
  if (i < R_OUTW)      { src = outW; dst = outW_bf; off = i; }
  else if (i < R_WIH)  { src = Wih;  dst = Wih_bf;  off = i - R_OUTW; }
  else if (i < R_WHH)  { src = Whh;  dst = Whh_bf;  off = i - R_WIH; }
  else if (i < R_ENCW) { src = encW; dst = encW_bf; off = i - R_WHH; }
  else if (i < R_PRDW) { src = prdW; dst = prdW_bf; off = i - R_ENCW; }
  else if (i < R_ENC)  { src = enc;  dst = enc_bf;  off = i - R_PRDW; }
  else {
    int e0 = (i - R_ENC) * 4;
    float4 v;
    v.x = (e0 + 0 < NO_) ? outB[e0 + 0] : 0.f;
    v.y = (e0 + 1 < NO_) ? outB[e0 + 1] : 0.f;
    v.z = (e0 + 2 < NO_) ? outB[e0 + 2] : 0.f;
    v.w = (e0 + 3 < NO_) ? outB[e0 + 3] : 0.f;
    *(float4*)&biasPad[e0] = v;
    return;
  }
  const float4 v = ((const float4*)src)[off];
  ushort4 o;
  o.x = f2bf(v.x); o.y = f2bf(v.y); o.z = f2bf(v.z); o.w = f2bf(v.w);
  ((ushort4*)dst)[off] = o;
}

// ---------------- embedding gather -> bf16 ----------------
__global__ void k_embed(const int* __restrict__ tg, const float* __restrict__ em,
                        unsigned short* __restrict__ x0) {
  int idx = blockIdx.x * 256 + threadIdx.x;
  int bu = idx >> 8;
  int kc = (idx & 255) << 2;
  int t = tg[bu];
  const float4 v = *(const float4*)&em[(long)t * H_ + kc];
  ushort4 o; o.x = f2bf(v.x); o.y = f2bf(v.y); o.z = f2bf(v.z); o.w = f2bf(v.w);
  *(ushort4*)&x0[bu * H_ + kc] = o;
}

// ---------------- ep projection (enc only; runs BEFORE the megakernel) ----------------
__global__ __launch_bounds__(256) void gemm_ep(
    const unsigned short* __restrict__ enc_bf, const unsigned short* __restrict__ encW_bf,
    const float* __restrict__ encB, float* __restrict__ ep)
{
  __shared__ unsigned short As[128 * 32];
  __shared__ unsigned short Bs[128 * 32];
  const int tid = threadIdx.x;
  const int n0 = blockIdx.x * 128, m0 = blockIdx.y * 128;
  const int K = H_, N = H_;
  const int lane = tid & 63, w = tid >> 6;
  const int wr = (w >> 1) * 64, wc = (w & 1) * 64;
  const int lr = lane & 15, lk = (lane >> 4) * 8;
  f32x4 acc[4][4] = {};

  for (int k0 = 0; k0 < K; k0 += 32) {
#pragma unroll
    for (int s = 0; s < 2; ++s) {
      int idx = (w * 2 + s) * 64 + lane;
      int row = idx >> 2, c8 = (idx & 3) * 8;
      gload_lds16(&enc_bf[(long)(m0 + row) * K + k0 + c8], &As[(w * 2 + s) * 512]);
      gload_lds16(&encW_bf[(long)(n0 + row) * K + k0 + c8], &Bs[(w * 2 + s) * 512]);
    }
    __syncthreads();
    bf16x8 aF[4], bF[4];
#pragma unroll
    for (int i = 0; i < 4; ++i) {
      aF[i] = *(const bf16x8*)&As[(wr + i * 16 + lr) * 32 + lk];
      bF[i] = *(const bf16x8*)&Bs[(wc + i * 16 + lr) * 32 + lk];
    }
#pragma unroll
    for (int i = 0; i < 4; ++i)
#pragma unroll
      for (int j = 0; j < 4; ++j)
        acc[i][j] = __builtin_amdgcn_mfma_f32_16x16x32_bf16(aF[i], bF[j], acc[i][j], 0, 0, 0);
    __syncthreads();
  }

  const int lq = (lane >> 4) * 4;
#pragma unroll
  for (int j = 0; j < 4; ++j) {
    int col = n0 + wc + j * 16 + lr;
    float bb = encB[col];
#pragma unroll
    for (int i = 0; i < 4; ++i) {
      int rowg = m0 + wr + i * 16 + lq;
#pragma unroll
      for (int r = 0; r < 4; ++r)
        ep[(long)(rowg + r) * N + col] = acc[i][j][r] + bb;
    }
  }
}

// ================= MEGAKERNEL: LSTM wavefront + pred-proj + logits GEMM =================
// blockIdx: 0-63 L0 | 64-127 X1 | 128-191 L1 | 192-255 X0 | 256-271 PP | 272-591 LG
// Sync cluster = blocks 0..271 (dispatched first; 2 blocks/CU -> all resident).
// PP/LG are pure consumers (U-deep buffers, no backpressure) -> no deadlock from
// late LG residency. All intra-kernel data moves via sc1 (LLC) loads/stores with
// tag-in-data (h bounded) or value-store+vmcnt+flag (unbounded values).
__global__ __launch_bounds__(256, 1) void mega(
    const unsigned short* __restrict__ x0_bf,
    const unsigned short* __restrict__ Whh0, const unsigned short* __restrict__ Wih0,
    const unsigned short* __restrict__ Whh1, const unsigned short* __restrict__ Wih1,
    const unsigned short* __restrict__ prdW_bf, const unsigned short* __restrict__ outW_bf,
    const float* __restrict__ bih0, const float* __restrict__ bhh0,
    const float* __restrict__ bih1, const float* __restrict__ bhh1,
    const float* __restrict__ prdB, const float* __restrict__ biasPad,
    const float* __restrict__ ep,             // [256][1024] f32 (pre-kernel)
    float* __restrict__ hbuf0, float* __restrict__ hbuf1,   // tagged ping-pongs (zeroed)
    float* __restrict__ xbuf,                 // [U][B][1024] tagged x1 (zeroed)
    float* __restrict__ xg1buf, int* __restrict__ flags1,
    float* __restrict__ xg0buf, int* __restrict__ flags0,
    float* __restrict__ x2tag,                // [U][B][1024] tagged x2 (zeroed)
    float* __restrict__ ppbuf, int* __restrict__ flagsP,    // flagsP zeroed
    float* __restrict__ out)
{
  __shared__ __align__(16) char smem[20992];
  float (*hs)[H_] = (float(*)[H_])smem;                       // 8KB (sync/PP)
  float (*part)[4][64][2] = (float(*)[4][64][2])(smem + 8192);// 4KB
  float* biasS = (float*)(smem + 8192 + 4096);                // 256B

  const int tid = threadIdx.x;
  const int bid = blockIdx.x & 63;
  const int w = tid >> 6, l = tid & 63;
  const int g = l >> 4, q = l & 15;
  const int row = g * 1024 + bid * 16 + q;
  const int kb = w * 256;

#define DOT_BODY(WREG, SRC)                                                              \
  _Pragma("unroll")                                                                      \
  for (int it = 0; it < 32; ++it) {                                                      \
    bf16x8 wv = WREG[it];                                                                \
    float4 h0a = *(const float4*)&SRC[0][kb + it * 8];                                   \
    float4 h0b = *(const float4*)&SRC[0][kb + it * 8 + 4];                               \
    float4 h1a = *(const float4*)&SRC[1][kb + it * 8];                                   \
    float4 h1b = *(const float4*)&SRC[1][kb + it * 8 + 4];                               \
    a00 += bf2f((unsigned short)wv[0]) * h0a.x + bf2f((unsigned short)wv[4]) * h0b.x;    \
    a01 += bf2f((unsigned short)wv[1]) * h0a.y + bf2f((unsigned short)wv[5]) * h0b.y;    \
    a02 += bf2f((unsigned short)wv[2]) * h0a.z + bf2f((unsigned short)wv[6]) * h0b.z;    \
    a03 += bf2f((unsigned short)wv[3]) * h0a.w + bf2f((unsigned short)wv[7]) * h0b.w;    \
    a10 += bf2f((unsigned short)wv[0]) * h1a.x + bf2f((unsigned short)wv[4]) * h1b.x;    \
    a11 += bf2f((unsigned short)wv[1]) * h1a.y + bf2f((unsigned short)wv[5]) * h1b.y;    \
    a12 += bf2f((unsigned short)wv[2]) * h1a.z + bf2f((unsigned short)wv[6]) * h1b.z;    \
    a13 += bf2f((unsigned short)wv[3]) * h1a.w + bf2f((unsigned short)wv[7]) * h1b.w;    \
  }

  if (blockIdx.x < 256 && ((blockIdx.x >> 6) == 0 || (blockIdx.x >> 6) == 2)) {
    // ================= recurrent layers L0 / L1 =================
    const int grp = blockIdx.x >> 6;
    const unsigned short* Whh = (grp == 0) ? Whh0 : Whh1;
    float* hbuf   = (grp == 0) ? hbuf0 : hbuf1;
    const float* xgbufR = (grp == 0) ? xg0buf : xg1buf;
    const int* flagsR   = (grp == 0) ? flags0 : flags1;
    bf16x8 wreg[32];
#pragma unroll
    for (int it = 0; it < 32; ++it)
      wreg[it] = *(const bf16x8*)&Whh[(long)row * H_ + kb + it * 8];
    __syncthreads();

    float creg = 0.f;
    for (int u = 0; u < U_; ++u) {
      const int p = u & 1;
      float xgi = 0.f, xgf = 0.f, xgg = 0.f, xgo = 0.f;
      if (tid < 32) {
        const int* fp = &flagsR[(u * 64 + bid) * 16];
        int fv;
        for (;;) {
          asm volatile("global_load_dword %0, %1, off sc1\n\ts_waitcnt vmcnt(0)"
                       : "=v"(fv) : "v"(fp) : "memory");
          if (fv != 0) break;
          __builtin_amdgcn_s_sleep(8);
        }
        const float* xb = &xgbufR[((u * 64 + bid) * 2 + (tid >> 4)) * 64];
        int qq = tid & 15;
        asm volatile("global_load_dword %0, %1, off sc1" : "=&v"(xgi) : "v"(xb + qq) : "memory");
        asm volatile("global_load_dword %0, %1, off sc1" : "=&v"(xgf) : "v"(xb + 16 + qq) : "memory");
        asm volatile("global_load_dword %0, %1, off sc1" : "=&v"(xgg) : "v"(xb + 32 + qq) : "memory");
        asm volatile("global_load_dword %0, %1, off sc1" : "=&v"(xgo) : "v"(xb + 48 + qq) : "memory");
      }
      float a00 = 0.f, a01 = 0.f, a02 = 0.f, a03 = 0.f;
      float a10 = 0.f, a11 = 0.f, a12 = 0.f, a13 = 0.f;
      if (u > 0) {
        const float thr = 4.0f * u - 2.0f;
        const float* base = hbuf + (u & 1) * 2 * H_;
        const float* pa = base + tid * 4;
        const float* pb = base + H_ + tid * 4;
        float4 va, vb;
        for (;;) {
          asm volatile("global_load_dwordx4 %0, %2, off sc1\n\t"
                       "global_load_dwordx4 %1, %3, off sc1\n\t"
                       "s_waitcnt vmcnt(0)"
                       : "=v"(va), "=v"(vb) : "v"(pa), "v"(pb) : "memory");
          if (va.x > thr && va.y > thr && va.z > thr && va.w > thr &&
              vb.x > thr && vb.y > thr && vb.z > thr && vb.w > thr) break;
          __builtin_amdgcn_s_sleep(8);
        }
        const float off = 4.0f * u;
        va.x -= off; va.y -= off; va.z -= off; va.w -= off;
        vb.x -= off; vb.y -= off; vb.z -= off; vb.w -= off;
        *(float4*)&hs[0][tid * 4] = va;     // wave-local staging
        *(float4*)&hs[1][tid * 4] = vb;
        DOT_BODY(wreg, hs)
      }
      part[p][w][l][0] = (a00 + a01) + (a02 + a03);
      part[p][w][l][1] = (a10 + a11) + (a12 + a13);
      if (tid < 32) {
        asm volatile("s_waitcnt vmcnt(0)"
                     : "+v"(xgi), "+v"(xgf), "+v"(xgg), "+v"(xgo) :: "memory");
      }
      __syncthreads();                       // single barrier per step
      if (tid < 32) {
        int b = tid >> 4, qq = tid & 15;
        float gi = part[p][0][qq][b] + part[p][1][qq][b] + part[p][2][qq][b]
                 + part[p][3][qq][b] + xgi;
        float gf = part[p][0][16 + qq][b] + part[p][1][16 + qq][b] + part[p][2][16 + qq][b]
                 + part[p][3][16 + qq][b] + xgf;
        float gc = part[p][0][32 + qq][b] + part[p][1][32 + qq][b] + part[p][2][32 + qq][b]
                 + part[p][3][32 + qq][b] + xgg;
        float go = part[p][0][48 + qq][b] + part[p][1][48 + qq][b] + part[p][2][48 + qq][b]
                 + part[p][3][48 + qq][b] + xgo;
        float i_ = fsig(gi), f_ = fsig(gf), g_ = ftanh(gc), o_ = fsig(go);
        creg = f_ * creg + i_ * g_;
        float h = o_ * ftanh(creg);
        int j = bid * 16 + qq;
        float tvx = h + 4.0f;
        if (grp == 0) {                      // publish x1(u) to X1
          const float* px = &xbuf[u * 2 * H_ + b * H_ + j];
          asm volatile("global_store_dword %0, %1, off sc1" :: "v"(px), "v"(tvx) : "memory");
        } else {                             // publish x2(u) to PP
          const float* px = &x2tag[u * 2 * H_ + b * H_ + j];
          asm volatile("global_store_dword %0, %1, off sc1" :: "v"(px), "v"(tvx) : "memory");
        }
        if (u < U_ - 1) {
          float tv = h + 4.0f * (u + 1);
          const float* pp2 = &hbuf[((u + 1) & 1) * 2 * H_ + b * H_ + j];
          asm volatile("global_store_dword %0, %1, off sc1" :: "v"(pp2), "v"(tv) : "memory");
        }
      }
    }
  } else if (blockIdx.x < 256) {
    // ================= x-projection groups X1 (grp 1) / X0 (grp 3) =================
    const bool isX1 = ((blockIdx.x >> 6) == 1);
    const unsigned short* Wih = isX1 ? Wih1 : Wih0;
    const float* bihp = isX1 ? bih1 : bih0;
    const float* bhhp = isX1 ? bhh1 : bhh0;
    float* xgbufW = isX1 ? xg1buf : xg0buf;
    int* flagsW   = isX1 ? flags1 : flags0;
    bf16x8 wreg[32];
#pragma unroll
    for (int it = 0; it < 32; ++it)
      wreg[it] = *(const bf16x8*)&Wih[(long)row * H_ + kb + it * 8];
    if (tid < 64) {
      int rr = (tid >> 4) * 1024 + bid * 16 + (tid & 15);
      biasS[tid] = bihp[rr] + bhhp[rr];
    }
    __syncthreads();

    for (int u = 0; u < U_; ++u) {
      const int p = u & 1;
      if (isX1) {
        const float* base = xbuf + u * 2 * H_;
        const float* pa = base + tid * 4;
        const float* pb = base + H_ + tid * 4;
        float4 va, vb;
        for (;;) {
          asm volatile("global_load_dwordx4 %0, %2, off sc1\n\t"
                       "global_load_dwordx4 %1, %3, off sc1\n\t"
                       "s_waitcnt vmcnt(0)"
                       : "=v"(va), "=v"(vb) : "v"(pa), "v"(pb) : "memory");
          if (va.x > 2.f && va.y > 2.f && va.z > 2.f && va.w > 2.f &&
              vb.x > 2.f && vb.y > 2.f && vb.z > 2.f && vb.w > 2.f) break;
          __builtin_amdgcn_s_sleep(8);
        }
        va.x -= 4.f; va.y -= 4.f; va.z -= 4.f; va.w -= 4.f;
        vb.x -= 4.f; vb.y -= 4.f; vb.z -= 4.f; vb.w -= 4.f;
        *(float4*)&hs[0][tid * 4] = va;
        *(float4*)&hs[1][tid * 4] = vb;
      } else {
        ushort4 xa = *(const ushort4*)&x0_bf[(0 * U_ + u) * H_ + tid * 4];
        ushort4 xb = *(const ushort4*)&x0_bf[(1 * U_ + u) * H_ + tid * 4];
        float4 va, vb;
        va.x = bf2f(xa.x); va.y = bf2f(xa.y); va.z = bf2f(xa.z); va.w = bf2f(xa.w);
        vb.x = bf2f(xb.x); vb.y = bf2f(xb.y); vb.z = bf2f(xb.z); vb.w = bf2f(xb.w);
        *(float4*)&hs[0][tid * 4] = va;
        *(float4*)&hs[1][tid * 4] = vb;
      }

      float a00 = 0.f, a01 = 0.f, a02 = 0.f, a03 = 0.f;
      float a10 = 0.f, a11 = 0.f, a12 = 0.f, a13 = 0.f;
      DOT_BODY(wreg, hs)
      part[p][w][l][0] = (a00 + a01) + (a02 + a03);
      part[p][w][l][1] = (a10 + a11) + (a12 + a13);
      __syncthreads();
      if (tid < 128) {
        int b = tid >> 6, ll = tid & 63;
        float s = part[p][0][ll][b] + part[p][1][ll][b] + part[p][2][ll][b]
                + part[p][3][ll][b] + biasS[ll];
        const float* pw = &xgbufW[((u * 64 + bid) * 2 + b) * 64 + ll];
        asm volatile("global_store_dword %0, %1, off sc1" :: "v"(pw), "v"(s) : "memory");
        asm volatile("s_waitcnt vmcnt(0)" ::: "memory");
      }
      __syncthreads();
      if (tid == 0) {
        int one = 1;
        const int* fp = &flagsW[(u * 64 + bid) * 16];
        asm volatile("global_store_dword %0, %1, off sc1" :: "v"(fp), "v"(one) : "memory");
      }
    }
  } else if (blockIdx.x < 272) {
    // ================= PP group: pp[u] = x2(u) * prdW^T + prdB (16 blocks) ==========
    const int pbid = blockIdx.x - 256;         // 0..15, owns cols [pbid*64, +64)
    bf16x8 wreg[32];
#pragma unroll
    for (int it = 0; it < 32; ++it)
      wreg[it] = *(const bf16x8*)&prdW_bf[(long)(pbid * 64 + l) * H_ + kb + it * 8];
    if (tid < 64) biasS[tid] = prdB[pbid * 64 + tid];
    __syncthreads();

    for (int u = 0; u < U_; ++u) {
      const int p = u & 1;
      const float* base = x2tag + u * 2 * H_;
      const float* pa = base + tid * 4;
      const float* pb = base + H_ + tid * 4;
      float4 va, vb;
      for (;;) {
        asm volatile("global_load_dwordx4 %0, %2, off sc1\n\t"
                     "global_load_dwordx4 %1, %3, off sc1\n\t"
                     "s_waitcnt vmcnt(0)"
                     : "=v"(va), "=v"(vb) : "v"(pa), "v"(pb) : "memory");
        if (va.x > 2.f && va.y > 2.f && va.z > 2.f && va.w > 2.f &&
            vb.x > 2.f && vb.y > 2.f && vb.z > 2.f && vb.w > 2.f) break;
        __builtin_amdgcn_s_sleep(8);
      }
      va.x -= 4.f; va.y -= 4.f; va.z -= 4.f; va.w -= 4.f;
      vb.x -= 4.f; vb.y -= 4.f; vb.z -= 4.f; vb.w -= 4.f;
      *(float4*)&hs[0][tid * 4] = va;
      *(float4*)&hs[1][tid * 4] = vb;

      float a00 = 0.f, a01 = 0.f, a02 = 0.f, a03 = 0.f;
      float a10 = 0.f, a11 = 0.f, a12 = 0.f, a13 = 0.f;
      DOT_BODY(wreg, hs)
      part[p][w][l][0] = (a00 + a01) + (a02 + a03);
      part[p][w][l][1] = (a10 + a11) + (a12 + a13);
      __syncthreads();
      if (tid < 128) {
        int b = tid >> 6, ll = tid & 63;
        float s = part[p][0][ll][b] + part[p][1][ll][b] + part[p][2][ll][b]
                + part[p][3][ll][b] + biasS[ll];
        const float* pw = &ppbuf[((u * 16 + pbid) * 2 + b) * 64 + ll];
        asm volatile("global_store_dword %0, %1, off sc1" :: "v"(pw), "v"(s) : "memory");
        asm volatile("s_waitcnt vmcnt(0)" ::: "memory");
      }
      __syncthreads();
      if (tid == 0) {
        int one = 1;
        const int* fp = &flagsP[(u * 16 + pbid) * 16];
        asm volatile("global_store_dword %0, %1, off sc1" :: "v"(fp), "v"(one) : "memory");
      }
    }
  } else {
    // ================= LG group: logits tiles (320 blocks) =================
    // lgid -> (uc, col80); col80 -> (b, np). Tile = 128 rows (fixed b, all t) x
    // 128 cols, for 16 consecutive u. A = bf16(relu(ep + pp[u])) built on the fly.
    const int lgid = blockIdx.x - 272;         // 0..319
    const int col80 = lgid % 80;
    const int uc = lgid / 80;                  // u in [uc*16, uc*16+16)
    const int bb = col80 & 1;
    const int np = col80 >> 1;                 // 0..39
    const int n0 = np * 128;
    unsigned short* As = (unsigned short*)smem;            // [128][32] bf16, 8KB
    unsigned short* Bs = (unsigned short*)(smem + 8192);   // [128][32] bf16, 8KB
    float* eb  = (float*)smem;                             // [32][132] f32 overlay
    float* pps = (float*)(smem + 16896);                   // [1024] f32 (disjoint)
    const int lane = tid & 63, w4 = tid >> 6;
    const int wr = (w4 >> 1) * 64, wc = (w4 & 1) * 64;
    const int lr = lane & 15, lk = (lane >> 4) * 8;
    const int lq = (lane >> 4) * 4;
    float bv[4];
#pragma unroll
    for (int j = 0; j < 4; ++j) bv[j] = biasPad[n0 + wc + j * 16 + lr];

    for (int u = uc * 16; u < uc * 16 + 16; ++u) {
      // wait all 16 PP flags for this u
      {
        int fv = 1;
        const int* fp = &flagsP[(u * 16 + (lane & 15)) * 16];
        for (;;) {
          if (lane < 16) {
            asm volatile("global_load_dword %0, %1, off sc1\n\ts_waitcnt vmcnt(0)"
                         : "=v"(fv) : "v"(fp) : "memory");
          }
          if (__all(fv != 0)) break;
          __builtin_amdgcn_s_sleep(8);
        }
      }
      __syncthreads();                         // eb (prev u) fully consumed
      // stage pp row for (u, bb) into LDS: 256 thr x float4 (sc1, one RTT)
      {
        int col = tid * 4, pbid = col >> 6, off = col & 63;
        const float* pa2 = &ppbuf[((u * 16 + pbid) * 2 + bb) * 64 + off];
        float4 pv;
        asm volatile("global_load_dwordx4 %0, %1, off sc1\n\ts_waitcnt vmcnt(0)"
                     : "=v"(pv) : "v"(pa2) : "memory");
        *(float4*)&pps[col] = pv;
      }
      __syncthreads();

      f32x4 acc[4][4] = {};
      for (int kt = 0; kt < 32; ++kt) {
        const int k0 = kt * 32;
        // A: relu(ep + pp) -> bf16 -> LDS (4 reps x ushort4)
#pragma unroll
        for (int rep = 0; rep < 4; ++rep) {
          int idx = rep * 256 + tid;
          int arow = idx >> 3, c4 = (idx & 7) * 4;
          float4 ev = *(const float4*)&ep[(long)(bb * 128 + arow) * H_ + k0 + c4];
          float4 pv = *(const float4*)&pps[k0 + c4];
          ushort4 o;
          o.x = f2bf(fmaxf(ev.x + pv.x, 0.f));
          o.y = f2bf(fmaxf(ev.y + pv.y, 0.f));
          o.z = f2bf(fmaxf(ev.z + pv.z, 0.f));
          o.w = f2bf(fmaxf(ev.w + pv.w, 0.f));
          *(ushort4*)&As[arow * 32 + c4] = o;
        }
        // B: outW panel via global_load_lds
#pragma unroll
        for (int s2 = 0; s2 < 2; ++s2) {
          int idx = (w4 * 2 + s2) * 64 + lane;
          int brow = idx >> 2, c8 = (idx & 3) * 8;
          gload_lds16(&outW_bf[(long)(n0 + brow) * H_ + k0 + c8], &Bs[(w4 * 2 + s2) * 512]);
        }
        __syncthreads();
        bf16x8 aF[4], bF[4];
#pragma unroll
        for (int i = 0; i < 4; ++i) {
          aF[i] = *(const bf16x8*)&As[(wr + i * 16 + lr) * 32 + lk];
          bF[i] = *(const bf16x8*)&Bs[(wc + i * 16 + lr) * 32 + lk];
        }
#pragma unroll
        for (int i = 0; i < 4; ++i)
#pragma unroll
          for (int j = 0; j < 4; ++j)
            acc[i][j] = __builtin_amdgcn_mfma_f32_16x16x32_bf16(aF[i], bF[j], acc[i][j], 0, 0, 0);
        __syncthreads();
      }
      // epilogue: LDS-bounce 4 chunks of 32 rows -> 512B-contiguous row writes
#pragma unroll
      for (int cp = 0; cp < 4; ++cp) {
        __syncthreads();
        if ((wr == 0) == (cp < 2)) {
#pragma unroll
          for (int ii = 0; ii < 2; ++ii) {
            int i = (cp & 1) * 2 + ii;
#pragma unroll
            for (int j = 0; j < 4; ++j) {
              int col = wc + j * 16 + lr;
#pragma unroll
              for (int r = 0; r < 4; ++r) {
                int lrow = wr + i * 16 + lq + r - cp * 32;
                eb[lrow * 132 + col] = acc[i][j][r] + bv[j];
              }
            }
          }
        }
        __syncthreads();
        {
          int rt = tid >> 3, ci = tid & 7;
          int trow = cp * 32 + rt;
          long grow = ((long)(bb * 128 + trow)) * 64 + u;
          float* crow = out + grow * NO_ + n0;
          const float* er = &eb[rt * 132];
#pragma unroll
          for (int k2 = 0; k2 < 4; ++k2) {
            int col = ci * 4 + k2 * 32;
            float4 v = *(const float4*)&er[col];
            int gc = n0 + col;
            if (gc + 4 <= NO_) {
              *(float4*)&crow[col] = v;
            } else if (gc < NO_) {
              float tmp[4] = {v.x, v.y, v.z, v.w};
#pragma unroll
              for (int e = 0; e < 4; ++e)
                if (gc + e < NO_) crow[col + e] = tmp[e];
            }
          }
        }
      }
    }
  }
#undef DOT_BODY
}

extern "C" void kernel_launch(void* const* d_in, const int* in_sizes, int n_in,
                              void* d_out, int out_size, void* d_ws, size_t ws_size,
                              hipStream_t stream)
{
  const float* enc   = (const float*)d_in[0];
  const int*   tg    = (const int*)d_in[1];
  const float* em    = (const float*)d_in[2];
  const float* Wih   = (const float*)d_in[3];
  const float* Whh   = (const float*)d_in[4];
  const float* bih   = (const float*)d_in[5];
  const float* bhh   = (const float*)d_in[6];
  const float* encW  = (const float*)d_in[7];
  const float* encB  = (const float*)d_in[8];
  const float* prdW  = (const float*)d_in[9];
  const float* prdB  = (const float*)d_in[10];
  const float* outW  = (const float*)d_in[11];
  const float* outB  = (const float*)d_in[12];
  float* out = (float*)d_out;
  char* ws = (char*)d_ws;

  // workspace layout (bytes)
  unsigned short* outW_bf = (unsigned short*)(ws + 0);         // 5120*1024*2
  unsigned short* Wih_bf  = (unsigned short*)(ws + 10485760);
  unsigned short* Whh_bf  = (unsigned short*)(ws + 27262976);
  unsigned short* encW_bf = (unsigned short*)(ws + 44040192);
  unsigned short* prdW_bf = (unsigned short*)(ws + 46137344);
  unsigned short* enc_bf  = (unsigned short*)(ws + 48234496);
  unsigned short* x0_bf   = (unsigned short*)(ws + 48758784);
  float* xg1buf = (float*)(ws + 49545216);                     // 2MB
  float* hbufL0 = (float*)(ws + 51642368);                     // 16,384
  // old jt region (32MB, base 51,659,008) hosts the new comm buffers:
  int*   flags0 = (int*)(ws + 51659008);                       // 262,144
  float* xg0buf = (float*)(ws + 51921152);                     // 2,097,152
  float* x2tag  = (float*)(ws + 54018304);                     // 524,288
  float* ppbuf  = (float*)(ws + 54542592);                     // 524,288
  int*   flagsP = (int*)(ws + 55066880);                       // 65,536
  float* ep     = (float*)(ws + 55132416);                     // 1,048,576
  float* hbufL1 = (float*)(ws + 85213440);                     // 16,384
  float* biasPad = (float*)(ws + 85229824);                    // 20,480
  float* xbuf = (float*)(ws + 85250304);                       // 524,288
  int* flags1 = (int*)(ws + 85774592);                         // 262,144 -> 86,036,736

  hipMemsetAsync(hbufL0, 0, 16384, stream);
  hipMemsetAsync(hbufL1, 0, 86036736 - 85213440, stream);      // hbufL1+biasPad+xbuf+flags1
  hipMemsetAsync(flags0, 0, 262144, stream);
  hipMemsetAsync(x2tag, 0, 524288, stream);
  hipMemsetAsync(flagsP, 0, 65536, stream);

  k_cvt_all<<<R_BIAS / 256, 256, 0, stream>>>(
      outW, Wih, Whh, encW, prdW, enc, outB,
      outW_bf, Wih_bf, Whh_bf, encW_bf, prdW_bf, enc_bf, biasPad);
  k_embed<<<(B_ * U_ * H_ / 4) / 256, 256, 0, stream>>>(tg, em, x0_bf);
  gemm_ep<<<dim3(8, 2), 256, 0, stream>>>(enc_bf, encW_bf, encB, ep);

  mega<<<592, 256, 0, stream>>>(
      x0_bf,
      Whh_bf, Wih_bf,                            // layer 0
      Whh_bf + 4096 * H_, Wih_bf + 4096 * H_,    // layer 1
      prdW_bf, outW_bf,
      bih, bhh, bih + 4096, bhh + 4096,
      prdB, biasPad, ep,
      hbufL0, hbufL1, xbuf,
      xg1buf, flags1, xg0buf, flags0,
      x2tag, ppbuf, flagsP, out);
}

// Round 15
// 682.203 us; speedup vs baseline: 2.2266x; 2.2266x over previous
//
#include <hip/hip_runtime.h>
#include <hip/hip_bf16.h>

#define B_ 2
#define T_ 128
#define U_ 64
#define H_ 1024
#define NO_ 5001

typedef __attribute__((ext_vector_type(8))) short bf16x8;
typedef __attribute__((ext_vector_type(4))) float f32x4;

__device__ __forceinline__ float bf2f(unsigned short s) {
  unsigned int u = ((unsigned int)s) << 16;
  float f; __builtin_memcpy(&f, &u, 4); return f;
}
__device__ __forceinline__ unsigned short f2bf(float f) {
  unsigned int u; __builtin_memcpy(&u, &f, 4);
  u = u + 0x7FFFu + ((u >> 16) & 1u);   // round-to-nearest-even
  return (unsigned short)(u >> 16);
}
__device__ __forceinline__ float fsig(float x) {
  x = fminf(fmaxf(x, -30.f), 30.f);
  float e = __expf(-x);
  return __builtin_amdgcn_rcpf(1.f + e);
}
__device__ __forceinline__ float ftanh(float x) {
  x = fminf(fmaxf(x, -15.f), 15.f);
  float e = __expf(2.f * x);
  return (e - 1.f) * __builtin_amdgcn_rcpf(e + 1.f);
}

__device__ __forceinline__ void gload_lds16(const unsigned short* g, unsigned short* l) {
  __builtin_amdgcn_global_load_lds(
      (const __attribute__((address_space(1))) unsigned int*)g,
      (__attribute__((address_space(3))) unsigned int*)l,
      16, 0, 0);
}

// ---------------- merged f32->bf16 conversions + bias pad + EMBED (one dispatch) ----------------
#define R_OUTW 1280256
#define R_WIH  (R_OUTW + 2097152)
#define R_WHH  (R_WIH + 2097152)
#define R_ENCW (R_WHH + 262144)
#define R_PRDW (R_ENCW + 262144)
#define R_ENC  (R_PRDW + 65536)
#define R_BIAS (R_ENC + 1280)
#define R_EMB  (R_BIAS + 32768)     // embed: B*U*H/4 float4 chunks

__global__ void k_cvt_all(
    const float* __restrict__ outW, const float* __restrict__ Wih,
    const float* __restrict__ Whh,  const float* __restrict__ encW,
    const float* __restrict__ prdW, const float* __restrict__ enc,
    const float* __restrict__ outB,
    const int* __restrict__ tg, const float* __restrict__ em,
    unsigned short* __restrict__ outW_bf, unsigned short* __restrict__ Wih_bf,
    unsigned short* __restrict__ Whh_bf,  unsigned short* __restrict__ encW_bf,
    unsigned short* __restrict__ prdW_bf, unsigned short* __restrict__ enc_bf,
    float* __restrict__ biasPad, unsigned short* __restrict__ x0_bf)
{
  int i = blockIdx.x * 256 + threadIdx.x;
  const float* src; unsigned short* dst; int off;
  if (i < R_OUTW)      { src = outW; dst = outW_bf; off = i; }
  else if (i < R_WIH)  { src = Wih;  dst = Wih_bf;  off = i - R_OUTW; }
  else if (i < R_WHH)  { src = Whh;  dst = Whh_bf;  off = i - R_WIH; }
  else if (i < R_ENCW) { src = encW; dst = encW_bf; off = i - R_WHH; }
  else if (i < R_PRDW) { src = prdW; dst = prdW_bf; off = i - R_ENCW; }
  else if (i < R_ENC)  { src = enc;  dst = enc_bf;  off = i - R_PRDW; }
  else if (i < R_BIAS) {
    int e0 = (i - R_ENC) * 4;
    float4 v;
    v.x = (e0 + 0 < NO_) ? outB[e0 + 0] : 0.f;
    v.y = (e0 + 1 < NO_) ? outB[e0 + 1] : 0.f;
    v.z = (e0 + 2 < NO_) ? outB[e0 + 2] : 0.f;
    v.w = (e0 + 3 < NO_) ? outB[e0 + 3] : 0.f;
    *(float4*)&biasPad[e0] = v;
    return;
  } else {                               // embedding gather -> bf16
    int idx = i - R_BIAS;                // [0, B*U*H/4)
    int bu = idx >> 8;
    int kc = (idx & 255) << 2;
    int t = tg[bu];
    const float4 v = *(const float4*)&em[(long)t * H_ + kc];
    ushort4 o; o.x = f2bf(v.x); o.y = f2bf(v.y); o.z = f2bf(v.z); o.w = f2bf(v.w);
    *(ushort4*)&x0_bf[bu * H_ + kc] = o;
    return;
  }
  const float4 v = ((const float4*)src)[off];
  ushort4 o;
  o.x = f2bf(v.x); o.y = f2bf(v.y); o.z = f2bf(v.z); o.w = f2bf(v.w);
  ((ushort4*)dst)[off] = o;
}

// ---------------- ep + pp projections in ONE launch (grid (8,3)) ----------------
__global__ __launch_bounds__(256) void gemm_proj(
    const unsigned short* __restrict__ enc_bf, const unsigned short* __restrict__ x2_bf,
    const unsigned short* __restrict__ encW_bf, const unsigned short* __restrict__ prdW_bf,
    const float* __restrict__ encB, const float* __restrict__ prdB,
    float* __restrict__ ep, float* __restrict__ pp)
{
  __shared__ unsigned short As[128 * 32];
  __shared__ unsigned short Bs[128 * 32];
  const int tid = threadIdx.x;
  const unsigned short* A; const unsigned short* W; const float* b1; float* C;
  int m0;
  if (blockIdx.y < 2) { A = enc_bf; W = encW_bf; b1 = encB; C = ep; m0 = blockIdx.y * 128; }
  else                { A = x2_bf;  W = prdW_bf; b1 = prdB; C = pp; m0 = 0; }
  const int n0 = blockIdx.x * 128;
  const int K = H_, N = H_;
  const int lane = tid & 63, w = tid >> 6;
  const int wr = (w >> 1) * 64, wc = (w & 1) * 64;
  const int lr = lane & 15, lk = (lane >> 4) * 8;
  f32x4 acc[4][4] = {};

  for (int k0 = 0; k0 < K; k0 += 32) {
#pragma unroll
    for (int s = 0; s < 2; ++s) {
      int idx = (w * 2 + s) * 64 + lane;
      int row = idx >> 2, c8 = (idx & 3) * 8;
      gload_lds16(&A[(long)(m0 + row) * K + k0 + c8], &As[(w * 2 + s) * 512]);
      gload_lds16(&W[(long)(n0 + row) * K + k0 + c8], &Bs[(w * 2 + s) * 512]);
    }
    __syncthreads();
    bf16x8 aF[4], bF[4];
#pragma unroll
    for (int i = 0; i < 4; ++i) {
      aF[i] = *(const bf16x8*)&As[(wr + i * 16 + lr) * 32 + lk];
      bF[i] = *(const bf16x8*)&Bs[(wc + i * 16 + lr) * 32 + lk];
    }
#pragma unroll
    for (int i = 0; i < 4; ++i)
#pragma unroll
      for (int j = 0; j < 4; ++j)
        acc[i][j] = __builtin_amdgcn_mfma_f32_16x16x32_bf16(aF[i], bF[j], acc[i][j], 0, 0, 0);
    __syncthreads();
  }

  const int lq = (lane >> 4) * 4;
#pragma unroll
  for (int j = 0; j < 4; ++j) {
    int col = n0 + wc + j * 16 + lr;
    float bb = b1[col];
#pragma unroll
    for (int i = 0; i < 4; ++i) {
      int rowg = m0 + wr + i * 16 + lq;
#pragma unroll
      for (int r = 0; r < 4; ++r)
        C[(long)(rowg + r) * N + col] = acc[i][j][r] + bb;
    }
  }
}

// ---------------- 256x256 pipelined logits GEMM with FUSED joint A-build ----------------
// A[r][k] = bf16(relu(ep[rowgrp][k] + pp[b*64+u][k])) built in-phase (no jt tensor).
// B staged via global_load_lds, counted vmcnt (4 units/tile -> waits of 2).
#define STAGE_B(kt2, kh, rb) \
  gload_lds16(bSrc[rb] + (kt2) * 64 + (kh) * 32, \
              &Bs_f[((((kt2) & 1) * 2 + (kh)) * 8192) + ((rb) * 128 + wv * 16) * 32])

__global__ __launch_bounds__(512, 1) void gemm_logits_f(
    const float* __restrict__ ep, const float* __restrict__ pp,
    const unsigned short* __restrict__ W,
    const float* __restrict__ biasPad, float* __restrict__ C)
{
  __shared__ __align__(16) unsigned short lds_all[65536];   // 128 KB
  unsigned short* As_f = lds_all;            // [buf][khalf][256][32]
  unsigned short* Bs_f = lds_all + 32768;
  const int tid = threadIdx.x;
  const int lane = tid & 63, wv = tid >> 6;
  const int wm = wv >> 2, wn = wv & 3;
  int swzb = (blockIdx.x & 7) * 160 + (blockIdx.x >> 3);
  const int n0 = (swzb >> 6) * 256;
  const int m0 = (swzb & 63) * 256;
  const int NT = H_ / 64;                    // 16
  const int N = NO_;

  const unsigned short* bSrc[2];
#pragma unroll
  for (int rb = 0; rb < 2; ++rb) {
    int rl = rb * 128 + (tid >> 2);
    int c2s = (tid & 3) ^ ((rl >> 1) & 3);
    bSrc[rb] = W + (long)(n0 + rl) * H_ + c2s * 8;
  }
  int aOff[8], bOff[4];
#pragma unroll
  for (int i = 0; i < 8; ++i) {
    int r = wm * 128 + i * 16 + (lane & 15);
    aOff[i] = r * 32 + (((lane >> 4) ^ ((r >> 1) & 3)) * 8);
  }
#pragma unroll
  for (int j = 0; j < 4; ++j) {
    int r = wn * 64 + j * 16 + (lane & 15);
    bOff[j] = r * 32 + (((lane >> 4) ^ ((r >> 1) & 3)) * 8);
  }

  // A-build sources: tile row rA of 256 -> ep row (m0>>6)+(rA>>6), pp row b*64+(rA&63)
  const int rA = tid >> 1;
  const int halfa = tid & 1;                 // builds chunks 2*halfa, 2*halfa+1
  const float* eprow = ep + (long)((m0 >> 6) + (rA >> 6)) * H_;
  const float* pprow = pp + (long)(((m0 >> 13) << 6) + (rA & 63)) * H_;
  const int abase = rA * 32;
  const int axor = (rA >> 1) & 3;

  auto BUILD_A = [&](int kt2, int kh) {
    const int k0 = kt2 * 64 + kh * 32;
    const int bufb = ((kt2 & 1) * 2 + kh) * 8192;
#pragma unroll
    for (int s = 0; s < 2; ++s) {
      int cc = halfa * 2 + s;
      int c8 = k0 + cc * 8;
      float4 e0 = *(const float4*)&eprow[c8];
      float4 e1 = *(const float4*)&eprow[c8 + 4];
      float4 p0 = *(const float4*)&pprow[c8];
      float4 p1 = *(const float4*)&pprow[c8 + 4];
      ushort4 o0, o1;
      o0.x = f2bf(fmaxf(e0.x + p0.x, 0.f));
      o0.y = f2bf(fmaxf(e0.y + p0.y, 0.f));
      o0.z = f2bf(fmaxf(e0.z + p0.z, 0.f));
      o0.w = f2bf(fmaxf(e0.w + p0.w, 0.f));
      o1.x = f2bf(fmaxf(e1.x + p1.x, 0.f));
      o1.y = f2bf(fmaxf(e1.y + p1.y, 0.f));
      o1.z = f2bf(fmaxf(e1.z + p1.z, 0.f));
      o1.w = f2bf(fmaxf(e1.w + p1.w, 0.f));
      int slot = cc ^ axor;
      *(ushort4*)&As_f[bufb + abase + slot * 8] = o0;
      *(ushort4*)&As_f[bufb + abase + slot * 8 + 4] = o1;
    }
  };

  f32x4 acc[8][4] = {};

  // prologue: build A(0) both halves; issue B(0) 4 units
  BUILD_A(0, 0); BUILD_A(0, 1);
  STAGE_B(0, 0, 0); STAGE_B(0, 0, 1); STAGE_B(0, 1, 0); STAGE_B(0, 1, 1);

  for (int kt = 0; kt < NT; ++kt) {
    const int b = kt & 1;
    asm volatile("s_waitcnt vmcnt(2)" ::: "memory");   // kt.k0 B-units arrived
    __builtin_amdgcn_s_barrier();
    __builtin_amdgcn_sched_barrier(0);
    {   // phase 0: khalf 0
      const int base = (b * 2 + 0) * 8192;
      bf16x8 aF[8], bF[4];
#pragma unroll
      for (int i = 0; i < 8; ++i) aF[i] = *(const bf16x8*)&As_f[base + aOff[i]];
#pragma unroll
      for (int j = 0; j < 4; ++j) bF[j] = *(const bf16x8*)&Bs_f[base + bOff[j]];
      if (kt + 1 < NT) {
        BUILD_A(kt + 1, 0);                  // f32 loads self-drain in-phase
        STAGE_B(kt + 1, 0, 0); STAGE_B(kt + 1, 0, 1);
      }
      __builtin_amdgcn_s_setprio(1);
#pragma unroll
      for (int i = 0; i < 8; ++i)
#pragma unroll
        for (int j = 0; j < 4; ++j)
          acc[i][j] = __builtin_amdgcn_mfma_f32_16x16x32_bf16(aF[i], bF[j], acc[i][j], 0, 0, 0);
      __builtin_amdgcn_s_setprio(0);
    }
    if (kt + 1 < NT) { asm volatile("s_waitcnt vmcnt(2)" ::: "memory"); }
    else             { asm volatile("s_waitcnt vmcnt(0)" ::: "memory"); }
    __builtin_amdgcn_s_barrier();
    __builtin_amdgcn_sched_barrier(0);
    {   // phase 1: khalf 1
      const int base = (b * 2 + 1) * 8192;
      bf16x8 aF[8], bF[4];
#pragma unroll
      for (int i = 0; i < 8; ++i) aF[i] = *(const bf16x8*)&As_f[base + aOff[i]];
#pragma unroll
      for (int j = 0; j < 4; ++j) bF[j] = *(const bf16x8*)&Bs_f[base + bOff[j]];
      if (kt + 1 < NT) {
        BUILD_A(kt + 1, 1);
        STAGE_B(kt + 1, 1, 0); STAGE_B(kt + 1, 1, 1);
      }
      __builtin_amdgcn_s_setprio(1);
#pragma unroll
      for (int i = 0; i < 8; ++i)
#pragma unroll
        for (int j = 0; j < 4; ++j)
          acc[i][j] = __builtin_amdgcn_mfma_f32_16x16x32_bf16(aF[i], bF[j], acc[i][j], 0, 0, 0);
      __builtin_amdgcn_s_setprio(0);
    }
  }

  // epilogue: LDS-bounce, contiguous row writes
  float* eb = (float*)lds_all;               // [64][261] f32
  const int lq = (lane >> 4) * 4;
  float bv4[4];
#pragma unroll
  for (int j = 0; j < 4; ++j) bv4[j] = biasPad[n0 + wn * 64 + j * 16 + (lane & 15)];

#pragma unroll
  for (int cp = 0; cp < 4; ++cp) {
    __syncthreads();
#pragma unroll
    for (int ii = 0; ii < 2; ++ii) {
      int rbase = wm * 32 + ii * 16 + lq;
#pragma unroll
      for (int j = 0; j < 4; ++j) {
        int col = wn * 64 + j * 16 + (lane & 15);
#pragma unroll
        for (int r = 0; r < 4; ++r)
          eb[(rbase + r) * 261 + col] = acc[cp * 2 + ii][j][r] + bv4[j];
      }
    }
    __syncthreads();
    {
      int rl = tid >> 3, ci = tid & 7;
      long grow = (long)m0 + (rl >> 5) * 128 + cp * 32 + (rl & 31);
      float* crow = C + grow * N + n0;
      const float* er = &eb[rl * 261];
#pragma unroll
      for (int k = 0; k < 8; ++k) {
        int col = ci * 4 + k * 32;
        float4 v = *(const float4*)&er[col];
        int gc = n0 + col;
        if (gc + 4 <= N) {
          *(float4*)&crow[col] = v;
        } else if (gc < N) {
          float tmp[4] = {v.x, v.y, v.z, v.w};
#pragma unroll
          for (int e = 0; e < 4; ++e)
            if (gc + e < N) crow[col + e] = tmp[e];
        }
      }
    }
  }
}

// ---------------- fused 2-layer wavefront LSTM, 4 groups x 64 blocks x 256 thr ----------------
// (round-13 version, unchanged — proven 303 us)
__global__ __launch_bounds__(256, 1) void lstm_fused3(
    const unsigned short* __restrict__ x0_bf,
    const unsigned short* __restrict__ Whh0,
    const unsigned short* __restrict__ Wih0,
    const unsigned short* __restrict__ Whh1,
    const unsigned short* __restrict__ Wih1,
    const float* __restrict__ bih0, const float* __restrict__ bhh0,
    const float* __restrict__ bih1, const float* __restrict__ bhh1,
    unsigned short* __restrict__ x2_bf,
    float* __restrict__ hbuf0,
    float* __restrict__ hbuf1,
    float* __restrict__ xbuf,
    float* __restrict__ xg1buf, int* __restrict__ flags1,
    float* __restrict__ xg0buf, int* __restrict__ flags0)
{
  __shared__ float hs[2][H_];
  __shared__ float part[2][4][64][2];
  __shared__ float biasS[64];

  const int tid = threadIdx.x;
  const int grp = blockIdx.x >> 6;           // 0=L0, 1=X1, 2=L1, 3=X0
  const int bid = blockIdx.x & 63;
  const int w = tid >> 6, l = tid & 63;
  const int g = l >> 4, q = l & 15;
  const int row = g * 1024 + bid * 16 + q;
  const int kb = w * 256;

#define DOT_BODY(WREG, SRC)                                                              \
  _Pragma("unroll")                                                                      \
  for (int it = 0; it < 32; ++it) {                                                      \
    bf16x8 wv = WREG[it];                                                                \
    float4 h0a = *(const float4*)&SRC[0][kb + it * 8];                                   \
    float4 h0b = *(const float4*)&SRC[0][kb + it * 8 + 4];                               \
    float4 h1a = *(const float4*)&SRC[1][kb + it * 8];                                   \
    float4 h1b = *(const float4*)&SRC[1][kb + it * 8 + 4];                               \
    a00 += bf2f((unsigned short)wv[0]) * h0a.x + bf2f((unsigned short)wv[4]) * h0b.x;    \
    a01 += bf2f((unsigned short)wv[1]) * h0a.y + bf2f((unsigned short)wv[5]) * h0b.y;    \
    a02 += bf2f((unsigned short)wv[2]) * h0a.z + bf2f((unsigned short)wv[6]) * h0b.z;    \
    a03 += bf2f((unsigned short)wv[3]) * h0a.w + bf2f((unsigned short)wv[7]) * h0b.w;    \
    a10 += bf2f((unsigned short)wv[0]) * h1a.x + bf2f((unsigned short)wv[4]) * h1b.x;    \
    a11 += bf2f((unsigned short)wv[1]) * h1a.y + bf2f((unsigned short)wv[5]) * h1b.y;    \
    a12 += bf2f((unsigned short)wv[2]) * h1a.z + bf2f((unsigned short)wv[6]) * h1b.z;    \
    a13 += bf2f((unsigned short)wv[3]) * h1a.w + bf2f((unsigned short)wv[7]) * h1b.w;    \
  }

  if (grp == 0 || grp == 2) {
    const unsigned short* Whh = (grp == 0) ? Whh0 : Whh1;
    float* hbuf   = (grp == 0) ? hbuf0 : hbuf1;
    const float* xgbufR = (grp == 0) ? xg0buf : xg1buf;
    const int* flagsR   = (grp == 0) ? flags0 : flags1;
    bf16x8 wreg[32];
#pragma unroll
    for (int it = 0; it < 32; ++it)
      wreg[it] = *(const bf16x8*)&Whh[(long)row * H_ + kb + it * 8];
    __syncthreads();

    float creg = 0.f;
    for (int u = 0; u < U_; ++u) {
      const int p = u & 1;
      float xgi = 0.f, xgf = 0.f, xgg = 0.f, xgo = 0.f;
      if (tid < 32) {
        const int* fp = &flagsR[(u * 64 + bid) * 16];
        int fv;
        for (;;) {
          asm volatile("global_load_dword %0, %1, off sc1\n\ts_waitcnt vmcnt(0)"
                       : "=v"(fv) : "v"(fp) : "memory");
          if (fv != 0) break;
          __builtin_amdgcn_s_sleep(8);
        }
        const float* xb = &xgbufR[((u * 64 + bid) * 2 + (tid >> 4)) * 64];
        int qq = tid & 15;
        asm volatile("global_load_dword %0, %1, off sc1" : "=&v"(xgi) : "v"(xb + qq) : "memory");
        asm volatile("global_load_dword %0, %1, off sc1" : "=&v"(xgf) : "v"(xb + 16 + qq) : "memory");
        asm volatile("global_load_dword %0, %1, off sc1" : "=&v"(xgg) : "v"(xb + 32 + qq) : "memory");
        asm volatile("global_load_dword %0, %1, off sc1" : "=&v"(xgo) : "v"(xb + 48 + qq) : "memory");
      }
      float a00 = 0.f, a01 = 0.f, a02 = 0.f, a03 = 0.f;
      float a10 = 0.f, a11 = 0.f, a12 = 0.f, a13 = 0.f;
      if (u > 0) {
        const float thr = 4.0f * u - 2.0f;
        const float* base = hbuf + (u & 1) * 2 * H_;
        const float* pa = base + tid * 4;
        const float* pb = base + H_ + tid * 4;
        float4 va, vb;
        for (;;) {
          asm volatile("global_load_dwordx4 %0, %2, off sc1\n\t"
                       "global_load_dwordx4 %1, %3, off sc1\n\t"
                       "s_waitcnt vmcnt(0)"
                       : "=v"(va), "=v"(vb) : "v"(pa), "v"(pb) : "memory");
          if (va.x > thr && va.y > thr && va.z > thr && va.w > thr &&
              vb.x > thr && vb.y > thr && vb.z > thr && vb.w > thr) break;
          __builtin_amdgcn_s_sleep(8);
        }
        const float off = 4.0f * u;
        va.x -= off; va.y -= off; va.z -= off; va.w -= off;
        vb.x -= off; vb.y -= off; vb.z -= off; vb.w -= off;
        *(float4*)&hs[0][tid * 4] = va;
        *(float4*)&hs[1][tid * 4] = vb;
        DOT_BODY(wreg, hs)
      }
      part[p][w][l][0] = (a00 + a01) + (a02 + a03);
      part[p][w][l][1] = (a10 + a11) + (a12 + a13);
      if (tid < 32) {
        asm volatile("s_waitcnt vmcnt(0)"
                     : "+v"(xgi), "+v"(xgf), "+v"(xgg), "+v"(xgo) :: "memory");
      }
      __syncthreads();
      if (tid < 32) {
        int b = tid >> 4, qq = tid & 15;
        float gi = part[p][0][qq][b] + part[p][1][qq][b] + part[p][2][qq][b]
                 + part[p][3][qq][b] + xgi;
        float gf = part[p][0][16 + qq][b] + part[p][1][16 + qq][b] + part[p][2][16 + qq][b]
                 + part[p][3][16 + qq][b] + xgf;
        float gc = part[p][0][32 + qq][b] + part[p][1][32 + qq][b] + part[p][2][32 + qq][b]
                 + part[p][3][32 + qq][b] + xgg;
        float go = part[p][0][48 + qq][b] + part[p][1][48 + qq][b] + part[p][2][48 + qq][b]
                 + part[p][3][48 + qq][b] + xgo;
        float i_ = fsig(gi), f_ = fsig(gf), g_ = ftanh(gc), o_ = fsig(go);
        creg = f_ * creg + i_ * g_;
        float h = o_ * ftanh(creg);
        int j = bid * 16 + qq;
        if (grp == 0) {
          float tvx = h + 4.0f;
          const float* px = &xbuf[u * 2 * H_ + b * H_ + j];
          asm volatile("global_store_dword %0, %1, off sc1" :: "v"(px), "v"(tvx) : "memory");
        } else {
          x2_bf[(b * U_ + u) * H_ + j] = f2bf(h);
        }
        if (u < U_ - 1) {
          float tv = h + 4.0f * (u + 1);
          const float* pp2 = &hbuf[((u + 1) & 1) * 2 * H_ + b * H_ + j];
          asm volatile("global_store_dword %0, %1, off sc1" :: "v"(pp2), "v"(tv) : "memory");
        }
      }
    }
  } else {
    const bool isX1 = (grp == 1);
    const unsigned short* Wih = isX1 ? Wih1 : Wih0;
    const float* bihp = isX1 ? bih1 : bih0;
    const float* bhhp = isX1 ? bhh1 : bhh0;
    float* xgbufW = isX1 ? xg1buf : xg0buf;
    int* flagsW   = isX1 ? flags1 : flags0;
    bf16x8 wreg[32];
#pragma unroll
    for (int it = 0; it < 32; ++it)
      wreg[it] = *(const bf16x8*)&Wih[(long)row * H_ + kb + it * 8];
    if (tid < 64) {
      int rr = (tid >> 4) * 1024 + bid * 16 + (tid & 15);
      biasS[tid] = bihp[rr] + bhhp[rr];
    }
    __syncthreads();

    for (int u = 0; u < U_; ++u) {
      const int p = u & 1;
      if (isX1) {
        const float* base = xbuf + u * 2 * H_;
        const float* pa = base + tid * 4;
        const float* pb = base + H_ + tid * 4;
        float4 va, vb;
        for (;;) {
          asm volatile("global_load_dwordx4 %0, %2, off sc1\n\t"
                       "global_load_dwordx4 %1, %3, off sc1\n\t"
                       "s_waitcnt vmcnt(0)"
                       : "=v"(va), "=v"(vb) : "v"(pa), "v"(pb) : "memory");
          if (va.x > 2.f && va.y > 2.f && va.z > 2.f && va.w > 2.f &&
              vb.x > 2.f && vb.y > 2.f && vb.z > 2.f && vb.w > 2.f) break;
          __builtin_amdgcn_s_sleep(8);
        }
        va.x -= 4.f; va.y -= 4.f; va.z -= 4.f; va.w -= 4.f;
        vb.x -= 4.f; vb.y -= 4.f; vb.z -= 4.f; vb.w -= 4.f;
        *(float4*)&hs[0][tid * 4] = va;
        *(float4*)&hs[1][tid * 4] = vb;
      } else {
        ushort4 xa = *(const ushort4*)&x0_bf[(0 * U_ + u) * H_ + tid * 4];
        ushort4 xb = *(const ushort4*)&x0_bf[(1 * U_ + u) * H_ + tid * 4];
        float4 va, vb;
        va.x = bf2f(xa.x); va.y = bf2f(xa.y); va.z = bf2f(xa.z); va.w = bf2f(xa.w);
        vb.x = bf2f(xb.x); vb.y = bf2f(xb.y); vb.z = bf2f(xb.z); vb.w = bf2f(xb.w);
        *(float4*)&hs[0][tid * 4] = va;
        *(float4*)&hs[1][tid * 4] = vb;
      }

      float a00 = 0.f, a01 = 0.f, a02 = 0.f, a03 = 0.f;
      float a10 = 0.f, a11 = 0.f, a12 = 0.f, a13 = 0.f;
      DOT_BODY(wreg, hs)
      part[p][w][l][0] = (a00 + a01) + (a02 + a03);
      part[p][w][l][1] = (a10 + a11) + (a12 + a13);
      __syncthreads();
      if (tid < 128) {
        int b = tid >> 6, ll = tid & 63;
        float s = part[p][0][ll][b] + part[p][1][ll][b] + part[p][2][ll][b]
                + part[p][3][ll][b] + biasS[ll];
        const float* pw = &xgbufW[((u * 64 + bid) * 2 + b) * 64 + ll];
        asm volatile("global_store_dword %0, %1, off sc1" :: "v"(pw), "v"(s) : "memory");
        asm volatile("s_waitcnt vmcnt(0)" ::: "memory");
      }
      __syncthreads();
      if (tid == 0) {
        int one = 1;
        const int* fp = &flagsW[(u * 64 + bid) * 16];
        asm volatile("global_store_dword %0, %1, off sc1" :: "v"(fp), "v"(one) : "memory");
      }
    }
  }
#undef DOT_BODY
}

extern "C" void kernel_launch(void* const* d_in, const int* in_sizes, int n_in,
                              void* d_out, int out_size, void* d_ws, size_t ws_size,
                              hipStream_t stream)
{
  const float* enc   = (const float*)d_in[0];
  const int*   tg    = (const int*)d_in[1];
  const float* em    = (const float*)d_in[2];
  const float* Wih   = (const float*)d_in[3];
  const float* Whh   = (const float*)d_in[4];
  const float* bih   = (const float*)d_in[5];
  const float* bhh   = (const float*)d_in[6];
  const float* encW  = (const float*)d_in[7];
  const float* encB  = (const float*)d_in[8];
  const float* prdW  = (const float*)d_in[9];
  const float* prdB  = (const float*)d_in[10];
  const float* outW  = (const float*)d_in[11];
  const float* outB  = (const float*)d_in[12];
  float* out = (float*)d_out;
  char* ws = (char*)d_ws;

  // workspace layout (bytes)
  unsigned short* outW_bf = (unsigned short*)(ws + 0);         // 10,485,760
  unsigned short* Wih_bf  = (unsigned short*)(ws + 10485760);
  unsigned short* Whh_bf  = (unsigned short*)(ws + 27262976);
  unsigned short* encW_bf = (unsigned short*)(ws + 44040192);
  unsigned short* prdW_bf = (unsigned short*)(ws + 46137344);
  unsigned short* enc_bf  = (unsigned short*)(ws + 48234496);
  unsigned short* x0_bf   = (unsigned short*)(ws + 48758784);
  unsigned short* x2_bf   = (unsigned short*)(ws + 49283072);
  float* xg1buf = (float*)(ws + 49545216);                     // 2MB, live during LSTM
  float* hbufL0 = (float*)(ws + 51642368);                     // 16,384
  int*   flags0 = (int*)(ws + 51659008);                       // 262,144 (old jt region)
  float* xg0buf = (float*)(ws + 51921152);                     // 2,097,152
  float* hbufL1 = (float*)(ws + 85213440);                     // 16,384
  float* biasPad = (float*)(ws + 85229824);                    // 20,480
  float* xbuf = (float*)(ws + 85250304);                       // 524,288
  int* flags1 = (int*)(ws + 85774592);                         // 262,144 -> 86,036,736
  float* ep = (float*)(ws + 49545216);                         // post-LSTM overlap w/ xg1buf
  float* pp = (float*)(ws + 49545216 + 1048576);

  hipMemsetAsync(hbufL0, 0, 16384, stream);
  hipMemsetAsync(hbufL1, 0, 86036736 - 85213440, stream);      // hbufL1..flags1 end
  hipMemsetAsync(flags0, 0, 262144, stream);

  k_cvt_all<<<R_EMB / 256, 256, 0, stream>>>(
      outW, Wih, Whh, encW, prdW, enc, outB, tg, em,
      outW_bf, Wih_bf, Whh_bf, encW_bf, prdW_bf, enc_bf, biasPad, x0_bf);

  // ---- fused 4-group LSTM (both input projections in-kernel) ----
  lstm_fused3<<<256, 256, 0, stream>>>(
      x0_bf,
      Whh_bf, Wih_bf,
      Whh_bf + 4096 * H_, Wih_bf + 4096 * H_,
      bih, bhh, bih + 4096, bhh + 4096,
      x2_bf, hbufL0, hbufL1, xbuf,
      xg1buf, flags1, xg0buf, flags0);

  // ---- projections (ep + pp in one launch) ----
  gemm_proj<<<dim3(8, 3), 256, 0, stream>>>(enc_bf, x2_bf, encW_bf, prdW_bf,
                                            encB, prdB, ep, pp);

  // ---- logits with fused joint A-build ----
  gemm_logits_f<<<1280, 512, 0, stream>>>(ep, pp, outW_bf, biasPad, out);
}

// Round 16
// 598.514 us; speedup vs baseline: 2.5380x; 1.1398x over previous
//
#include <hip/hip_runtime.h>
#include <hip/hip_bf16.h>

#define B_ 2
#define T_ 128
#define U_ 64
#define H_ 1024
#define NO_ 5001

typedef __attribute__((ext_vector_type(8))) short bf16x8;
typedef __attribute__((ext_vector_type(4))) float f32x4;

__device__ __forceinline__ float bf2f(unsigned short s) {
  unsigned int u = ((unsigned int)s) << 16;
  float f; __builtin_memcpy(&f, &u, 4); return f;
}
__device__ __forceinline__ unsigned short f2bf(float f) {
  unsigned int u; __builtin_memcpy(&u, &f, 4);
  u = u + 0x7FFFu + ((u >> 16) & 1u);   // round-to-nearest-even
  return (unsigned short)(u >> 16);
}
__device__ __forceinline__ float fsig(float x) {
  x = fminf(fmaxf(x, -30.f), 30.f);
  float e = __expf(-x);
  return __builtin_amdgcn_rcpf(1.f + e);
}
__device__ __forceinline__ float ftanh(float x) {
  x = fminf(fmaxf(x, -15.f), 15.f);
  float e = __expf(2.f * x);
  return (e - 1.f) * __builtin_amdgcn_rcpf(e + 1.f);
}

__device__ __forceinline__ void gload_lds16(const unsigned short* g, unsigned short* l) {
  __builtin_amdgcn_global_load_lds(
      (const __attribute__((address_space(1))) unsigned int*)g,
      (__attribute__((address_space(3))) unsigned int*)l,
      16, 0, 0);
}

// ---------------- merged f32->bf16 conversions + bias pad + embed (one dispatch) ----------------
#define R_OUTW 1280256
#define R_WIH  (R_OUTW + 2097152)
#define R_WHH  (R_WIH + 2097152)
#define R_ENCW (R_WHH + 262144)
#define R_PRDW (R_ENCW + 262144)
#define R_ENC  (R_PRDW + 65536)
#define R_BIAS (R_ENC + 1280)
#define R_EMB  (R_BIAS + 32768)     // embed: B*U*H/4 float4 chunks

__global__ void k_cvt_all(
    const float* __restrict__ outW, const float* __restrict__ Wih,
    const float* __restrict__ Whh,  const float* __restrict__ encW,
    const float* __restrict__ prdW, const float* __restrict__ enc,
    const float* __restrict__ outB,
    const int* __restrict__ tg, const float* __restrict__ em,
    unsigned short* __restrict__ outW_bf, unsigned short* __restrict__ Wih_bf,
    unsigned short* __restrict__ Whh_bf,  unsigned short* __restrict__ encW_bf,
    unsigned short* __restrict__ prdW_bf, unsigned short* __restrict__ enc_bf,
    float* __restrict__ biasPad, unsigned short* __restrict__ x0_bf)
{
  int i = blockIdx.x * 256 + threadIdx.x;
  const float* src; unsigned short* dst; int off;
  if (i < R_OUTW)      { src = outW; dst = outW_bf; off = i; }
  else if (i < R_WIH)  { src = Wih;  dst = Wih_bf;  off = i - R_OUTW; }
  else if (i < R_WHH)  { src = Whh;  dst = Whh_bf;  off = i - R_WIH; }
  else if (i < R_ENCW) { src = encW; dst = encW_bf; off = i - R_WHH; }
  else if (i < R_PRDW) { src = prdW; dst = prdW_bf; off = i - R_ENCW; }
  else if (i < R_ENC)  { src = enc;  dst = enc_bf;  off = i - R_PRDW; }
  else if (i < R_BIAS) {
    int e0 = (i - R_ENC) * 4;
    float4 v;
    v.x = (e0 + 0 < NO_) ? outB[e0 + 0] : 0.f;
    v.y = (e0 + 1 < NO_) ? outB[e0 + 1] : 0.f;
    v.z = (e0 + 2 < NO_) ? outB[e0 + 2] : 0.f;
    v.w = (e0 + 3 < NO_) ? outB[e0 + 3] : 0.f;
    *(float4*)&biasPad[e0] = v;
    return;
  } else {                               // embedding gather -> bf16
    int idx = i - R_BIAS;                // [0, B*U*H/4)
    int bu = idx >> 8;
    int kc = (idx & 255) << 2;
    int t = tg[bu];
    const float4 v = *(const float4*)&em[(long)t * H_ + kc];
    ushort4 o; o.x = f2bf(v.x); o.y = f2bf(v.y); o.z = f2bf(v.z); o.w = f2bf(v.w);
    *(ushort4*)&x0_bf[bu * H_ + kc] = o;
    return;
  }
  const float4 v = ((const float4*)src)[off];
  ushort4 o;
  o.x = f2bf(v.x); o.y = f2bf(v.y); o.z = f2bf(v.z); o.w = f2bf(v.w);
  ((ushort4*)dst)[off] = o;
}

// ---------------- ep + pp projections in ONE launch (grid (8,3)) ----------------
__global__ __launch_bounds__(256) void gemm_proj(
    const unsigned short* __restrict__ enc_bf, const unsigned short* __restrict__ x2_bf,
    const unsigned short* __restrict__ encW_bf, const unsigned short* __restrict__ prdW_bf,
    const float* __restrict__ encB, const float* __restrict__ prdB,
    float* __restrict__ ep, float* __restrict__ pp)
{
  __shared__ unsigned short As[128 * 32];
  __shared__ unsigned short Bs[128 * 32];
  const int tid = threadIdx.x;
  const unsigned short* A; const unsigned short* W; const float* b1; float* C;
  int m0;
  if (blockIdx.y < 2) { A = enc_bf; W = encW_bf; b1 = encB; C = ep; m0 = blockIdx.y * 128; }
  else                { A = x2_bf;  W = prdW_bf; b1 = prdB; C = pp; m0 = 0; }
  const int n0 = blockIdx.x * 128;
  const int K = H_, N = H_;
  const int lane = tid & 63, w = tid >> 6;
  const int wr = (w >> 1) * 64, wc = (w & 1) * 64;
  const int lr = lane & 15, lk = (lane >> 4) * 8;
  f32x4 acc[4][4] = {};

  for (int k0 = 0; k0 < K; k0 += 32) {
#pragma unroll
    for (int s = 0; s < 2; ++s) {
      int idx = (w * 2 + s) * 64 + lane;
      int row = idx >> 2, c8 = (idx & 3) * 8;
      gload_lds16(&A[(long)(m0 + row) * K + k0 + c8], &As[(w * 2 + s) * 512]);
      gload_lds16(&W[(long)(n0 + row) * K + k0 + c8], &Bs[(w * 2 + s) * 512]);
    }
    __syncthreads();
    bf16x8 aF[4], bF[4];
#pragma unroll
    for (int i = 0; i < 4; ++i) {
      aF[i] = *(const bf16x8*)&As[(wr + i * 16 + lr) * 32 + lk];
      bF[i] = *(const bf16x8*)&Bs[(wc + i * 16 + lr) * 32 + lk];
    }
#pragma unroll
    for (int i = 0; i < 4; ++i)
#pragma unroll
      for (int j = 0; j < 4; ++j)
        acc[i][j] = __builtin_amdgcn_mfma_f32_16x16x32_bf16(aF[i], bF[j], acc[i][j], 0, 0, 0);
    __syncthreads();
  }

  const int lq = (lane >> 4) * 4;
#pragma unroll
  for (int j = 0; j < 4; ++j) {
    int col = n0 + wc + j * 16 + lr;
    float bb = b1[col];
#pragma unroll
    for (int i = 0; i < 4; ++i) {
      int rowg = m0 + wr + i * 16 + lq;
#pragma unroll
      for (int r = 0; r < 4; ++r)
        C[(long)(rowg + r) * N + col] = acc[i][j][r] + bb;
    }
  }
}

// ---------------- 256x256 pipelined logits GEMM (round-8/13 proven version) ----------------
#define STAGE_A(kt2, kh, rb) \
  gload_lds16(aSrc[rb] + (kt2) * 64 + (kh) * 32, \
              &As_f[((((kt2) & 1) * 2 + (kh)) * 8192) + ((rb) * 128 + wv * 16) * 32])
#define STAGE_B(kt2, kh, rb) \
  gload_lds16(bSrc[rb] + (kt2) * 64 + (kh) * 32, \
              &Bs_f[((((kt2) & 1) * 2 + (kh)) * 8192) + ((rb) * 128 + wv * 16) * 32])

__global__ __launch_bounds__(512, 1) void gemm_logits(
    const unsigned short* __restrict__ A, const unsigned short* __restrict__ W,
    const float* __restrict__ biasPad, float* __restrict__ C, int M, int N, int K)
{
  __shared__ __align__(16) unsigned short lds_all[65536];   // 128 KB
  unsigned short* As_f = lds_all;
  unsigned short* Bs_f = lds_all + 32768;
  const int tid = threadIdx.x;
  const int lane = tid & 63, wv = tid >> 6;
  const int wm = wv >> 2, wn = wv & 3;
  int swzb = (blockIdx.x & 7) * 160 + (blockIdx.x >> 3);
  const int n0 = (swzb >> 6) * 256;
  const int m0 = (swzb & 63) * 256;
  const int NT = K / 64;

  const unsigned short* aSrc[2];
  const unsigned short* bSrc[2];
#pragma unroll
  for (int rb = 0; rb < 2; ++rb) {
    int rl = rb * 128 + (tid >> 2);
    int c2s = (tid & 3) ^ ((rl >> 1) & 3);
    aSrc[rb] = A + (long)(m0 + rl) * K + c2s * 8;
    bSrc[rb] = W + (long)(n0 + rl) * K + c2s * 8;
  }
  int aOff[8], bOff[4];
#pragma unroll
  for (int i = 0; i < 8; ++i) {
    int r = wm * 128 + i * 16 + (lane & 15);
    aOff[i] = r * 32 + (((lane >> 4) ^ ((r >> 1) & 3)) * 8);
  }
#pragma unroll
  for (int j = 0; j < 4; ++j) {
    int r = wn * 64 + j * 16 + (lane & 15);
    bOff[j] = r * 32 + (((lane >> 4) ^ ((r >> 1) & 3)) * 8);
  }

  f32x4 acc[8][4] = {};

  STAGE_A(0, 0, 0); STAGE_A(0, 0, 1); STAGE_B(0, 0, 0); STAGE_B(0, 0, 1);
  STAGE_A(0, 1, 0); STAGE_A(0, 1, 1); STAGE_B(0, 1, 0); STAGE_B(0, 1, 1);

  for (int kt = 0; kt < NT; ++kt) {
    const int b = kt & 1;
    asm volatile("s_waitcnt vmcnt(4)" ::: "memory");
    __builtin_amdgcn_s_barrier();
    __builtin_amdgcn_sched_barrier(0);
    {   // phase 0: khalf 0
      const int base = (b * 2 + 0) * 8192;
      bf16x8 aF[8], bF[4];
#pragma unroll
      for (int i = 0; i < 8; ++i) aF[i] = *(const bf16x8*)&As_f[base + aOff[i]];
#pragma unroll
      for (int j = 0; j < 4; ++j) bF[j] = *(const bf16x8*)&Bs_f[base + bOff[j]];
      if (kt + 1 < NT) {
        STAGE_A(kt + 1, 0, 0); STAGE_A(kt + 1, 0, 1);
        STAGE_B(kt + 1, 0, 0); STAGE_B(kt + 1, 0, 1);
        STAGE_A(kt + 1, 1, 0); STAGE_A(kt + 1, 1, 1);
      }
      __builtin_amdgcn_s_setprio(1);
#pragma unroll
      for (int i = 0; i < 8; ++i)
#pragma unroll
        for (int j = 0; j < 4; ++j)
          acc[i][j] = __builtin_amdgcn_mfma_f32_16x16x32_bf16(aF[i], bF[j], acc[i][j], 0, 0, 0);
      __builtin_amdgcn_s_setprio(0);
    }
    if (kt + 1 < NT) { asm volatile("s_waitcnt vmcnt(6)" ::: "memory"); }
    else             { asm volatile("s_waitcnt vmcnt(0)" ::: "memory"); }
    __builtin_amdgcn_s_barrier();
    __builtin_amdgcn_sched_barrier(0);
    {   // phase 1: khalf 1
      const int base = (b * 2 + 1) * 8192;
      bf16x8 aF[8], bF[4];
#pragma unroll
      for (int i = 0; i < 8; ++i) aF[i] = *(const bf16x8*)&As_f[base + aOff[i]];
#pragma unroll
      for (int j = 0; j < 4; ++j) bF[j] = *(const bf16x8*)&Bs_f[base + bOff[j]];
      if (kt + 1 < NT) { STAGE_B(kt + 1, 1, 0); STAGE_B(kt + 1, 1, 1); }
      __builtin_amdgcn_s_setprio(1);
#pragma unroll
      for (int i = 0; i < 8; ++i)
#pragma unroll
        for (int j = 0; j < 4; ++j)
          acc[i][j] = __builtin_amdgcn_mfma_f32_16x16x32_bf16(aF[i], bF[j], acc[i][j], 0, 0, 0);
      __builtin_amdgcn_s_setprio(0);
    }
  }

  // epilogue: LDS-bounce, contiguous row writes
  float* eb = (float*)lds_all;               // [64][261] f32
  const int lq = (lane >> 4) * 4;
  float bv4[4];
#pragma unroll
  for (int j = 0; j < 4; ++j) bv4[j] = biasPad[n0 + wn * 64 + j * 16 + (lane & 15)];

#pragma unroll
  for (int cp = 0; cp < 4; ++cp) {
    __syncthreads();
#pragma unroll
    for (int ii = 0; ii < 2; ++ii) {
      int rbase = wm * 32 + ii * 16 + lq;
#pragma unroll
      for (int j = 0; j < 4; ++j) {
        int col = wn * 64 + j * 16 + (lane & 15);
#pragma unroll
        for (int r = 0; r < 4; ++r)
          eb[(rbase + r) * 261 + col] = acc[cp * 2 + ii][j][r] + bv4[j];
      }
    }
    __syncthreads();
    {
      int rl = tid >> 3, ci = tid & 7;
      long grow = (long)m0 + (rl >> 5) * 128 + cp * 32 + (rl & 31);
      float* crow = C + grow * N + n0;
      const float* er = &eb[rl * 261];
#pragma unroll
      for (int k = 0; k < 8; ++k) {
        int col = ci * 4 + k * 32;
        float4 v = *(const float4*)&er[col];
        int gc = n0 + col;
        if (gc + 4 <= N) {
          *(float4*)&crow[col] = v;
        } else if (gc < N) {
          float tmp[4] = {v.x, v.y, v.z, v.w};
#pragma unroll
          for (int e = 0; e < 4; ++e)
            if (gc + e < N) crow[col + e] = tmp[e];
        }
      }
    }
  }
}

// ---------------- joint = bf16(relu(enc_p[b,t,:] + prd_p[b,u,:])) ----------------
__global__ void k_joint(const float* __restrict__ ep, const float* __restrict__ pp,
                        unsigned short* __restrict__ jt)
{
  int idx = blockIdx.x * 256 + threadIdx.x;
  int m = idx >> 8;
  int kc = (idx & 255) << 2;
  int erow = m >> 6;
  int prow = (m >> 13) * U_ + (m & 63);
  const float4 e = *(const float4*)&ep[erow * H_ + kc];
  const float4 p = *(const float4*)&pp[prow * H_ + kc];
  float4 s;
  s.x = fmaxf(e.x + p.x, 0.f); s.y = fmaxf(e.y + p.y, 0.f);
  s.z = fmaxf(e.z + p.z, 0.f); s.w = fmaxf(e.w + p.w, 0.f);
  ushort4 o; o.x = f2bf(s.x); o.y = f2bf(s.y); o.z = f2bf(s.z); o.w = f2bf(s.w);
  *(ushort4*)&jt[m * H_ + kc] = o;
}

// ---------------- fused 2-layer wavefront LSTM, 4 groups x 64 blocks x 256 thr ----------------
// (round-13 proven version — 303 us)
__global__ __launch_bounds__(256, 1) void lstm_fused3(
    const unsigned short* __restrict__ x0_bf,
    const unsigned short* __restrict__ Whh0,
    const unsigned short* __restrict__ Wih0,
    const unsigned short* __restrict__ Whh1,
    const unsigned short* __restrict__ Wih1,
    const float* __restrict__ bih0, const float* __restrict__ bhh0,
    const float* __restrict__ bih1, const float* __restrict__ bhh1,
    unsigned short* __restrict__ x2_bf,
    float* __restrict__ hbuf0,
    float* __restrict__ hbuf1,
    float* __restrict__ xbuf,
    float* __restrict__ xg1buf, int* __restrict__ flags1,
    float* __restrict__ xg0buf, int* __restrict__ flags0)
{
  __shared__ float hs[2][H_];
  __shared__ float part[2][4][64][2];
  __shared__ float biasS[64];

  const int tid = threadIdx.x;
  const int grp = blockIdx.x >> 6;           // 0=L0, 1=X1, 2=L1, 3=X0
  const int bid = blockIdx.x & 63;
  const int w = tid >> 6, l = tid & 63;
  const int g = l >> 4, q = l & 15;
  const int row = g * 1024 + bid * 16 + q;
  const int kb = w * 256;

#define DOT_BODY(WREG, SRC)                                                              \
  _Pragma("unroll")                                                                      \
  for (int it = 0; it < 32; ++it) {                                                      \
    bf16x8 wv = WREG[it];                                                                \
    float4 h0a = *(const float4*)&SRC[0][kb + it * 8];                                   \
    float4 h0b = *(const float4*)&SRC[0][kb + it * 8 + 4];                               \
    float4 h1a = *(const float4*)&SRC[1][kb + it * 8];                                   \
    float4 h1b = *(const float4*)&SRC[1][kb + it * 8 + 4];                               \
    a00 += bf2f((unsigned short)wv[0]) * h0a.x + bf2f((unsigned short)wv[4]) * h0b.x;    \
    a01 += bf2f((unsigned short)wv[1]) * h0a.y + bf2f((unsigned short)wv[5]) * h0b.y;    \
    a02 += bf2f((unsigned short)wv[2]) * h0a.z + bf2f((unsigned short)wv[6]) * h0b.z;    \
    a03 += bf2f((unsigned short)wv[3]) * h0a.w + bf2f((unsigned short)wv[7]) * h0b.w;    \
    a10 += bf2f((unsigned short)wv[0]) * h1a.x + bf2f((unsigned short)wv[4]) * h1b.x;    \
    a11 += bf2f((unsigned short)wv[1]) * h1a.y + bf2f((unsigned short)wv[5]) * h1b.y;    \
    a12 += bf2f((unsigned short)wv[2]) * h1a.z + bf2f((unsigned short)wv[6]) * h1b.z;    \
    a13 += bf2f((unsigned short)wv[3]) * h1a.w + bf2f((unsigned short)wv[7]) * h1b.w;    \
  }

  if (grp == 0 || grp == 2) {
    const unsigned short* Whh = (grp == 0) ? Whh0 : Whh1;
    float* hbuf   = (grp == 0) ? hbuf0 : hbuf1;
    const float* xgbufR = (grp == 0) ? xg0buf : xg1buf;
    const int* flagsR   = (grp == 0) ? flags0 : flags1;
    bf16x8 wreg[32];
#pragma unroll
    for (int it = 0; it < 32; ++it)
      wreg[it] = *(const bf16x8*)&Whh[(long)row * H_ + kb + it * 8];
    __syncthreads();

    float creg = 0.f;
    for (int u = 0; u < U_; ++u) {
      const int p = u & 1;
      float xgi = 0.f, xgf = 0.f, xgg = 0.f, xgo = 0.f;
      if (tid < 32) {
        const int* fp = &flagsR[(u * 64 + bid) * 16];
        int fv;
        for (;;) {
          asm volatile("global_load_dword %0, %1, off sc1\n\ts_waitcnt vmcnt(0)"
                       : "=v"(fv) : "v"(fp) : "memory");
          if (fv != 0) break;
          __builtin_amdgcn_s_sleep(8);
        }
        const float* xb = &xgbufR[((u * 64 + bid) * 2 + (tid >> 4)) * 64];
        int qq = tid & 15;
        asm volatile("global_load_dword %0, %1, off sc1" : "=&v"(xgi) : "v"(xb + qq) : "memory");
        asm volatile("global_load_dword %0, %1, off sc1" : "=&v"(xgf) : "v"(xb + 16 + qq) : "memory");
        asm volatile("global_load_dword %0, %1, off sc1" : "=&v"(xgg) : "v"(xb + 32 + qq) : "memory");
        asm volatile("global_load_dword %0, %1, off sc1" : "=&v"(xgo) : "v"(xb + 48 + qq) : "memory");
      }
      float a00 = 0.f, a01 = 0.f, a02 = 0.f, a03 = 0.f;
      float a10 = 0.f, a11 = 0.f, a12 = 0.f, a13 = 0.f;
      if (u > 0) {
        const float thr = 4.0f * u - 2.0f;
        const float* base = hbuf + (u & 1) * 2 * H_;
        const float* pa = base + tid * 4;
        const float* pb = base + H_ + tid * 4;
        float4 va, vb;
        for (;;) {
          asm volatile("global_load_dwordx4 %0, %2, off sc1\n\t"
                       "global_load_dwordx4 %1, %3, off sc1\n\t"
                       "s_waitcnt vmcnt(0)"
                       : "=v"(va), "=v"(vb) : "v"(pa), "v"(pb) : "memory");
          if (va.x > thr && va.y > thr && va.z > thr && va.w > thr &&
              vb.x > thr && vb.y > thr && vb.z > thr && vb.w > thr) break;
          __builtin_amdgcn_s_sleep(8);
        }
        const float off = 4.0f * u;
        va.x -= off; va.y -= off; va.z -= off; va.w -= off;
        vb.x -= off; vb.y -= off; vb.z -= off; vb.w -= off;
        *(float4*)&hs[0][tid * 4] = va;
        *(float4*)&hs[1][tid * 4] = vb;
        DOT_BODY(wreg, hs)
      }
      part[p][w][l][0] = (a00 + a01) + (a02 + a03);
      part[p][w][l][1] = (a10 + a11) + (a12 + a13);
      if (tid < 32) {
        asm volatile("s_waitcnt vmcnt(0)"
                     : "+v"(xgi), "+v"(xgf), "+v"(xgg), "+v"(xgo) :: "memory");
      }
      __syncthreads();
      if (tid < 32) {
        int b = tid >> 4, qq = tid & 15;
        float gi = part[p][0][qq][b] + part[p][1][qq][b] + part[p][2][qq][b]
                 + part[p][3][qq][b] + xgi;
        float gf = part[p][0][16 + qq][b] + part[p][1][16 + qq][b] + part[p][2][16 + qq][b]
                 + part[p][3][16 + qq][b] + xgf;
        float gc = part[p][0][32 + qq][b] + part[p][1][32 + qq][b] + part[p][2][32 + qq][b]
                 + part[p][3][32 + qq][b] + xgg;
        float go = part[p][0][48 + qq][b] + part[p][1][48 + qq][b] + part[p][2][48 + qq][b]
                 + part[p][3][48 + qq][b] + xgo;
        float i_ = fsig(gi), f_ = fsig(gf), g_ = ftanh(gc), o_ = fsig(go);
        creg = f_ * creg + i_ * g_;
        float h = o_ * ftanh(creg);
        int j = bid * 16 + qq;
        if (grp == 0) {
          float tvx = h + 4.0f;
          const float* px = &xbuf[u * 2 * H_ + b * H_ + j];
          asm volatile("global_store_dword %0, %1, off sc1" :: "v"(px), "v"(tvx) : "memory");
        } else {
          x2_bf[(b * U_ + u) * H_ + j] = f2bf(h);
        }
        if (u < U_ - 1) {
          float tv = h + 4.0f * (u + 1);
          const float* pp2 = &hbuf[((u + 1) & 1) * 2 * H_ + b * H_ + j];
          asm volatile("global_store_dword %0, %1, off sc1" :: "v"(pp2), "v"(tv) : "memory");
        }
      }
    }
  } else {
    const bool isX1 = (grp == 1);
    const unsigned short* Wih = isX1 ? Wih1 : Wih0;
    const float* bihp = isX1 ? bih1 : bih0;
    const float* bhhp = isX1 ? bhh1 : bhh0;
    float* xgbufW = isX1 ? xg1buf : xg0buf;
    int* flagsW   = isX1 ? flags1 : flags0;
    bf16x8 wreg[32];
#pragma unroll
    for (int it = 0; it < 32; ++it)
      wreg[it] = *(const bf16x8*)&Wih[(long)row * H_ + kb + it * 8];
    if (tid < 64) {
      int rr = (tid >> 4) * 1024 + bid * 16 + (tid & 15);
      biasS[tid] = bihp[rr] + bhhp[rr];
    }
    __syncthreads();

    for (int u = 0; u < U_; ++u) {
      const int p = u & 1;
      if (isX1) {
        const float* base = xbuf + u * 2 * H_;
        const float* pa = base + tid * 4;
        const float* pb = base + H_ + tid * 4;
        float4 va, vb;
        for (;;) {
          asm volatile("global_load_dwordx4 %0, %2, off sc1\n\t"
                       "global_load_dwordx4 %1, %3, off sc1\n\t"
                       "s_waitcnt vmcnt(0)"
                       : "=v"(va), "=v"(vb) : "v"(pa), "v"(pb) : "memory");
          if (va.x > 2.f && va.y > 2.f && va.z > 2.f && va.w > 2.f &&
              vb.x > 2.f && vb.y > 2.f && vb.z > 2.f && vb.w > 2.f) break;
          __builtin_amdgcn_s_sleep(8);
        }
        va.x -= 4.f; va.y -= 4.f; va.z -= 4.f; va.w -= 4.f;
        vb.x -= 4.f; vb.y -= 4.f; vb.z -= 4.f; vb.w -= 4.f;
        *(float4*)&hs[0][tid * 4] = va;
        *(float4*)&hs[1][tid * 4] = vb;
      } else {
        ushort4 xa = *(const ushort4*)&x0_bf[(0 * U_ + u) * H_ + tid * 4];
        ushort4 xb = *(const ushort4*)&x0_bf[(1 * U_ + u) * H_ + tid * 4];
        float4 va, vb;
        va.x = bf2f(xa.x); va.y = bf2f(xa.y); va.z = bf2f(xa.z); va.w = bf2f(xa.w);
        vb.x = bf2f(xb.x); vb.y = bf2f(xb.y); vb.z = bf2f(xb.z); vb.w = bf2f(xb.w);
        *(float4*)&hs[0][tid * 4] = va;
        *(float4*)&hs[1][tid * 4] = vb;
      }

      float a00 = 0.f, a01 = 0.f, a02 = 0.f, a03 = 0.f;
      float a10 = 0.f, a11 = 0.f, a12 = 0.f, a13 = 0.f;
      DOT_BODY(wreg, hs)
      part[p][w][l][0] = (a00 + a01) + (a02 + a03);
      part[p][w][l][1] = (a10 + a11) + (a12 + a13);
      __syncthreads();
      if (tid < 128) {
        int b = tid >> 6, ll = tid & 63;
        float s = part[p][0][ll][b] + part[p][1][ll][b] + part[p][2][ll][b]
                + part[p][3][ll][b] + biasS[ll];
        const float* pw = &xgbufW[((u * 64 + bid) * 2 + b) * 64 + ll];
        asm volatile("global_store_dword %0, %1, off sc1" :: "v"(pw), "v"(s) : "memory");
        asm volatile("s_waitcnt vmcnt(0)" ::: "memory");
      }
      __syncthreads();
      if (tid == 0) {
        int one = 1;
        const int* fp = &flagsW[(u * 64 + bid) * 16];
        asm volatile("global_store_dword %0, %1, off sc1" :: "v"(fp), "v"(one) : "memory");
      }
    }
  }
#undef DOT_BODY
}

extern "C" void kernel_launch(void* const* d_in, const int* in_sizes, int n_in,
                              void* d_out, int out_size, void* d_ws, size_t ws_size,
                              hipStream_t stream)
{
  const float* enc   = (const float*)d_in[0];
  const int*   tg    = (const int*)d_in[1];
  const float* em    = (const float*)d_in[2];
  const float* Wih   = (const float*)d_in[3];
  const float* Whh   = (const float*)d_in[4];
  const float* bih   = (const float*)d_in[5];
  const float* bhh   = (const float*)d_in[6];
  const float* encW  = (const float*)d_in[7];
  const float* encB  = (const float*)d_in[8];
  const float* prdW  = (const float*)d_in[9];
  const float* prdB  = (const float*)d_in[10];
  const float* outW  = (const float*)d_in[11];
  const float* outB  = (const float*)d_in[12];
  float* out = (float*)d_out;
  char* ws = (char*)d_ws;

  // workspace layout (bytes)
  unsigned short* outW_bf = (unsigned short*)(ws + 0);         // 10,485,760
  unsigned short* Wih_bf  = (unsigned short*)(ws + 10485760);
  unsigned short* Whh_bf  = (unsigned short*)(ws + 27262976);
  unsigned short* encW_bf = (unsigned short*)(ws + 44040192);
  unsigned short* prdW_bf = (unsigned short*)(ws + 46137344);
  unsigned short* enc_bf  = (unsigned short*)(ws + 48234496);
  unsigned short* x0_bf   = (unsigned short*)(ws + 48758784);
  unsigned short* x2_bf   = (unsigned short*)(ws + 49283072);
  float* xg1buf = (float*)(ws + 49545216);                     // 2MB, live during LSTM
  float* hbufL0 = (float*)(ws + 51642368);                     // 16,384
  unsigned short* jt = (unsigned short*)(ws + 51659008);       // 32MB -> ends 85,213,440
  // flags0/xg0buf alias the head of the jt region (time-disjoint: jt written by
  // k_joint only AFTER the LSTM completes) — proven in round 13.
  int*   flags0 = (int*)(ws + 51659008);                       // 262,144
  float* xg0buf = (float*)(ws + 51921152);                     // 2,097,152
  float* hbufL1 = (float*)(ws + 85213440);                     // 16,384
  float* biasPad = (float*)(ws + 85229824);                    // 20,480
  float* xbuf = (float*)(ws + 85250304);                       // 524,288
  int* flags1 = (int*)(ws + 85774592);                         // 262,144 -> 86,036,736
  float* ep = (float*)(ws + 49545216);                         // post-LSTM overlap w/ xg1buf
  float* pp = (float*)(ws + 49545216 + 1048576);

  hipMemsetAsync(hbufL0, 0, 16384, stream);
  hipMemsetAsync(hbufL1, 0, 86036736 - 85213440, stream);      // hbufL1..flags1 end
  hipMemsetAsync(flags0, 0, 262144, stream);

  k_cvt_all<<<R_EMB / 256, 256, 0, stream>>>(
      outW, Wih, Whh, encW, prdW, enc, outB, tg, em,
      outW_bf, Wih_bf, Whh_bf, encW_bf, prdW_bf, enc_bf, biasPad, x0_bf);

  // ---- fused 4-group LSTM (both input projections in-kernel) ----
  lstm_fused3<<<256, 256, 0, stream>>>(
      x0_bf,
      Whh_bf, Wih_bf,
      Whh_bf + 4096 * H_, Wih_bf + 4096 * H_,
      bih, bhh, bih + 4096, bhh + 4096,
      x2_bf, hbufL0, hbufL1, xbuf,
      xg1buf, flags1, xg0buf, flags0);

  // ---- projections (ep + pp in one launch) ----
  gemm_proj<<<dim3(8, 3), 256, 0, stream>>>(enc_bf, x2_bf, encW_bf, prdW_bf,
                                            encB, prdB, ep, pp);

  // ---- joint + logits ----
  k_joint<<<16384, 256, 0, stream>>>(ep, pp, jt);
  gemm_logits<<<1280, 512, 0, stream>>>(jt, outW_bf, biasPad, out, B_ * T_ * U_, NO_, H_);
}